// Round 11
// baseline (277.198 us; speedup 1.0000x reference)
//
#include <hip/hip_runtime.h>
#include <hip/hip_bf16.h>
#include <hip/hip_fp16.h>

#define DIMI 64
#define DIMO 40

#define NBK_SHIFT 9
#define NPBK 512
#define NBKMAX 256
#define BCAP 9216
#define CHUNK 4096

// ---------------- CSR build: LDS-sorted counting-sort path ----------------

__global__ void k_zero(int* __restrict__ p, int n) {
    int i = blockIdx.x * blockDim.x + threadIdx.x;
    if (i < n) p[i] = 0;
}

// Phase A: bin CHUNK edges into 512-node buckets; LDS sort; coalesced writeout.
// Records packed: (src << 9) | (dst & 511)
__global__ void k_binA(const int* __restrict__ src, const int* __restrict__ dst,
                       int* __restrict__ bcnt, int* __restrict__ ebP,
                       int E, int nbk) {
    __shared__ int h[NBKMAX];
    __shared__ int lb[NBKMAX];
    __shared__ int lc[NBKMAX];
    __shared__ int gb[NBKMAX];
    __shared__ int eb[CHUNK];
    __shared__ unsigned char ebB[CHUNK];
    int t = threadIdx.x;
    int e0 = blockIdx.x * CHUNK;
    int e1 = min(e0 + CHUNK, E);
    int nE = e1 - e0;
    h[t] = 0;
    __syncthreads();
    int d[CHUNK / 256], s[CHUNK / 256];
    #pragma unroll
    for (int u = 0; u < CHUNK / 256; u++) {
        int idx = e0 + t + u * 256;
        if (idx < e1) {
            d[u] = dst[idx];
            s[u] = src[idx];
            atomicAdd(&h[d[u] >> NBK_SHIFT], 1);
        }
    }
    __syncthreads();
    int orig = h[t];
    for (int o = 1; o < 256; o <<= 1) {
        int v = (t >= o) ? h[t - o] : 0;
        __syncthreads();
        h[t] += v;
        __syncthreads();
    }
    lb[t] = h[t] - orig;
    lc[t] = 0;
    gb[t] = orig ? atomicAdd(&bcnt[t], orig) : 0;
    __syncthreads();
    #pragma unroll
    for (int u = 0; u < CHUNK / 256; u++) {
        int idx = e0 + t + u * 256;
        if (idx < e1) {
            int b = d[u] >> NBK_SHIFT;
            int r = atomicAdd(&lc[b], 1);
            int slot = lb[b] + r;
            eb[slot] = (s[u] << NBK_SHIFT) | (d[u] & (NPBK - 1));
            ebB[slot] = (unsigned char)b;
        }
    }
    __syncthreads();
    for (int i = t; i < nE; i += 256) {
        int b = ebB[i];
        int slot = gb[b] + (i - lb[b]);
        if (slot < BCAP) ebP[(size_t)b * BCAP + slot] = eb[i];
    }
}

// Fused phase B+C with src-half split. Bins keyed (dlocal<<1)|half (1024).
// Emits off/mid/dinv dense + LDS-placed coalesced col. Computes own bucket
// prefix (no separate scan kernel).
__global__ void k_binBC(const int* __restrict__ bcnt, const int* __restrict__ ebP,
                        int* __restrict__ off, int* __restrict__ mid,
                        float* __restrict__ dinv, int* __restrict__ col,
                        int N, int nbk, int nHalf) {
    __shared__ int sb[256];
    __shared__ int sh[1024];
    __shared__ int ssum[256];
    __shared__ int so[1024];
    __shared__ int slc[1024];
    __shared__ int scol[BCAP];
    int b = blockIdx.x, t = threadIdx.x;
    // bucket global prefix
    int v = (t < nbk) ? min(bcnt[t], BCAP) : 0;
    sb[t] = v;
    __syncthreads();
    for (int o = 1; o < 256; o <<= 1) {
        int u = (t >= o) ? sb[t - o] : 0;
        __syncthreads();
        sb[t] += u;
        __syncthreads();
    }
    int gbase = (b > 0) ? sb[b - 1] : 0;
    int n = min(bcnt[b], BCAP);
    sh[t] = 0; sh[t + 256] = 0; sh[t + 512] = 0; sh[t + 768] = 0;
    __syncthreads();
    size_t base = (size_t)b * BCAP;
    for (int i = t; i < n; i += 256) {
        int e = ebP[base + i];
        int key = ((e & (NPBK - 1)) << 1) | ((e >> NBK_SHIFT) >= nHalf ? 1 : 0);
        atomicAdd(&sh[key], 1);
    }
    __syncthreads();
    int c0 = sh[4 * t], c1 = sh[4 * t + 1], c2 = sh[4 * t + 2], c3 = sh[4 * t + 3];
    int tsum = c0 + c1 + c2 + c3;
    ssum[t] = tsum;
    __syncthreads();
    for (int o = 1; o < 256; o <<= 1) {
        int u = (t >= o) ? ssum[t - o] : 0;
        __syncthreads();
        ssum[t] += u;
        __syncthreads();
    }
    int eb0 = ssum[t] - tsum;  // exclusive base for this thread's 4 bins
    so[4 * t] = eb0;
    so[4 * t + 1] = eb0 + c0;
    so[4 * t + 2] = eb0 + c0 + c1;
    so[4 * t + 3] = eb0 + c0 + c1 + c2;
    slc[4 * t] = 0; slc[4 * t + 1] = 0; slc[4 * t + 2] = 0; slc[4 * t + 3] = 0;
    int d0 = b << NBK_SHIFT;
    {
        int dd = d0 + 2 * t;           // dlocal = 2t : bins 4t(A), 4t+1(B)
        if (dd < N) {
            off[dd] = gbase + eb0;
            mid[dd] = gbase + eb0 + c0;
            dinv[dd] = rsqrtf((float)(c0 + c1 + 1));
        }
        dd = d0 + 2 * t + 1;           // dlocal = 2t+1 : bins 4t+2(A), 4t+3(B)
        if (dd < N) {
            off[dd] = gbase + eb0 + c0 + c1;
            mid[dd] = gbase + eb0 + c0 + c1 + c2;
            dinv[dd] = rsqrtf((float)(c2 + c3 + 1));
        }
    }
    if (t == 0 && b == nbk - 1) off[N] = gbase + n;  // sentinel
    __syncthreads();
    for (int i = t; i < n; i += 256) {
        int e = ebP[base + i];
        int srcv = e >> NBK_SHIFT;
        int key = ((e & (NPBK - 1)) << 1) | (srcv >= nHalf ? 1 : 0);
        int r = atomicAdd(&slc[key], 1);
        scol[so[key] + r] = srcv;
    }
    __syncthreads();
    for (int i = t; i < n; i += 256) col[gbase + i] = scol[i];
}

// ---------------- CSR build: fallback (random-write) path ----------------

__global__ void k_hist(const int* __restrict__ dst, int* __restrict__ counts, int E) {
    int i = blockIdx.x * blockDim.x + threadIdx.x;
    if (i < E) atomicAdd(&counts[dst[i]], 1);
}

__global__ void k_scatter(const int* __restrict__ src, const int* __restrict__ dst,
                          const int* __restrict__ off, int* __restrict__ cursor,
                          int* __restrict__ col, int E) {
    int i = blockIdx.x * blockDim.x + threadIdx.x;
    if (i < E) {
        int d = dst[i];
        int p = off[d] + atomicAdd(&cursor[d], 1);
        col[p] = src[i];
    }
}

__global__ void k_block_sums(const int* __restrict__ counts, int* __restrict__ partial, int n) {
    __shared__ int s[256];
    int i = blockIdx.x * 256 + threadIdx.x;
    s[threadIdx.x] = (i < n) ? counts[i] : 0;
    __syncthreads();
    for (int st = 128; st > 0; st >>= 1) {
        if (threadIdx.x < st) s[threadIdx.x] += s[threadIdx.x + st];
        __syncthreads();
    }
    if (threadIdx.x == 0) partial[blockIdx.x] = s[0];
}

__global__ void k_scan_partials(int* partial, int nb) {
    __shared__ int s[1024];
    int t = threadIdx.x;
    int orig = (t < nb) ? partial[t] : 0;
    s[t] = orig;
    __syncthreads();
    for (int o = 1; o < 1024; o <<= 1) {
        int v = (t >= o) ? s[t - o] : 0;
        __syncthreads();
        s[t] += v;
        __syncthreads();
    }
    if (t < nb) partial[t] = s[t] - orig;
}

// fallback: off/mid/dinv; mid = off[i+1] (all edges in pass A)
__global__ void k_scan_final(const int* __restrict__ counts, const int* __restrict__ partial,
                             int* __restrict__ off, int* __restrict__ mid,
                             float* __restrict__ dinv, int n) {
    __shared__ int s[256];
    int t = threadIdx.x;
    int i = blockIdx.x * 256 + t;
    int orig = (i < n) ? counts[i] : 0;
    s[t] = orig;
    __syncthreads();
    for (int o = 1; o < 256; o <<= 1) {
        int v = (t >= o) ? s[t - o] : 0;
        __syncthreads();
        s[t] += v;
        __syncthreads();
    }
    if (i < n) {
        off[i] = s[t] - orig + partial[blockIdx.x];
        mid[i] = s[t] + partial[blockIdx.x];
        dinv[i] = rsqrtf((float)(orig + 1));
        if (i == n - 1) off[n] = s[t] + partial[blockIdx.x];
    }
}

// ---------------- dense math ----------------

// Wc = W_sgc @ W_head; bc = b_sgc @ W_head + b_head; also zeroes bcnt.
__global__ void k_wc(const float* __restrict__ Wsgc, const float* __restrict__ bsgc,
                     const float* __restrict__ Whead, const float* __restrict__ bhead,
                     float* __restrict__ Wc, float* __restrict__ bc,
                     int* __restrict__ bcnt, int nbk) {
    __shared__ float sA[DIMI * DIMI];
    __shared__ float sB[DIMI * DIMO];
    int t = threadIdx.x;
    for (int i = t; i < nbk; i += 256) bcnt[i] = 0;
    for (int i = t; i < DIMI * DIMI; i += 256) sA[i] = Wsgc[i];
    for (int i = t; i < DIMI * DIMO; i += 256) sB[i] = Whead[i];
    __syncthreads();
    for (int o = t; o < DIMI * DIMO; o += 256) {
        int k = o / DIMO, j = o % DIMO;
        float a = 0.f;
        #pragma unroll
        for (int m = 0; m < DIMI; m++) a += sA[k * DIMI + m] * sB[m * DIMO + j];
        Wc[o] = a;
    }
    if (t < DIMO) {
        float a = bhead[t];
        #pragma unroll
        for (int m = 0; m < DIMI; m++) a += bsgc[m] * sB[m * DIMO + t];
        bc[t] = a;
    }
}

// u0 = dinv * (x @ Wc) -> unified fp16 rows, stride 40 (80B)
__global__ void k_projU(const float* __restrict__ x, const float* __restrict__ Wc,
                        const float* __restrict__ dinv, __half* __restrict__ y, int N) {
    __shared__ float sW[DIMI * DIMO];
    int t = threadIdx.x;
    for (int i = t; i < DIMI * DIMO; i += 256) sW[i] = Wc[i];
    __syncthreads();
    int node = blockIdx.x * 256 + t;
    if (node >= N) return;
    float di = dinv[node];
    const float4* xr = (const float4*)(x + (size_t)node * DIMI);
    float acc[DIMO];
    #pragma unroll
    for (int j = 0; j < DIMO; j++) acc[j] = 0.f;
    for (int k4 = 0; k4 < DIMI / 4; k4++) {
        float4 xv = xr[k4];
        int k = k4 * 4;
        #pragma unroll
        for (int j = 0; j < DIMO; j++)
            acc[j] += xv.x * sW[k * DIMO + j] + xv.y * sW[(k + 1) * DIMO + j]
                    + xv.z * sW[(k + 2) * DIMO + j] + xv.w * sW[(k + 3) * DIMO + j];
    }
    __half2* y2 = (__half2*)(y + (size_t)node * DIMO);
    #pragma unroll
    for (int p = 0; p < DIMO / 2; p++)
        y2[p] = __floats2half2_rn(di * acc[2 * p], di * acc[2 * p + 1]);
}

// Hop pass A: edges with src < N/2 (gather footprint = first 4MB slice).
// partial[node] = self + sum_A (unscaled, fp16) -> written to the hop's
// output buffer (overwritten by pass B).
__global__ void k_hopA(const __half* __restrict__ xin, __half* __restrict__ xpart,
                       const int* __restrict__ off, const int* __restrict__ mid,
                       const int* __restrict__ col, int N) {
    int gtid = blockIdx.x * blockDim.x + threadIdx.x;
    int node = gtid >> 6;
    int lane = threadIdx.x & 63;
    if (node >= N) return;
    int l = lane < DIMO ? lane : DIMO - 1;
    int rs = off[node];
    int cnt = mid[node] - rs;
    int cidx = (lane < cnt) ? col[rs + lane] : node;
    float acc = __half2float(xin[(size_t)node * DIMO + l]);  // self loop
    int cmain = cnt < 64 ? cnt : 64;
    int e = 0;
    for (; e + 8 <= cmain; e += 8) {
        float v[8];
        #pragma unroll
        for (int u = 0; u < 8; u++) {
            int c = __shfl(cidx, e + u, 64);
            v[u] = __half2float(xin[(size_t)c * DIMO + l]);
        }
        acc += ((v[0] + v[1]) + (v[2] + v[3])) + ((v[4] + v[5]) + (v[6] + v[7]));
    }
    for (; e + 4 <= cmain; e += 4) {
        float v[4];
        #pragma unroll
        for (int u = 0; u < 4; u++) {
            int c = __shfl(cidx, e + u, 64);
            v[u] = __half2float(xin[(size_t)c * DIMO + l]);
        }
        acc += (v[0] + v[1]) + (v[2] + v[3]);
    }
    for (; e < cmain; e++) {
        int c = __shfl(cidx, e, 64);
        acc += __half2float(xin[(size_t)c * DIMO + l]);
    }
    for (int e2 = 64; e2 < cnt; e2++)
        acc += __half2float(xin[(size_t)col[rs + e2] * DIMO + l]);
    if (lane < DIMO) xpart[(size_t)node * DIMO + lane] = __float2half(acc);
}

// Hop pass B: edges with src >= N/2 (second 4MB slice); reads partial,
// scales, writes final (fp16 mid-hop or fp32+bias final hop).
__global__ void k_hopB(const __half* __restrict__ xin, __half* __restrict__ xpart,
                       float* __restrict__ outF,
                       const int* __restrict__ off, const int* __restrict__ mid,
                       const int* __restrict__ col, const float* __restrict__ dinv,
                       const float* __restrict__ bc, int finalHop, int N) {
    int gtid = blockIdx.x * blockDim.x + threadIdx.x;
    int node = gtid >> 6;
    int lane = threadIdx.x & 63;
    if (node >= N) return;
    int l = lane < DIMO ? lane : DIMO - 1;
    int rs = mid[node];
    int cnt = off[node + 1] - rs;
    int cidx = (lane < cnt) ? col[rs + lane] : node;
    float acc = __half2float(xpart[(size_t)node * DIMO + l]);  // partial A
    int cmain = cnt < 64 ? cnt : 64;
    int e = 0;
    for (; e + 8 <= cmain; e += 8) {
        float v[8];
        #pragma unroll
        for (int u = 0; u < 8; u++) {
            int c = __shfl(cidx, e + u, 64);
            v[u] = __half2float(xin[(size_t)c * DIMO + l]);
        }
        acc += ((v[0] + v[1]) + (v[2] + v[3])) + ((v[4] + v[5]) + (v[6] + v[7]));
    }
    for (; e + 4 <= cmain; e += 4) {
        float v[4];
        #pragma unroll
        for (int u = 0; u < 4; u++) {
            int c = __shfl(cidx, e + u, 64);
            v[u] = __half2float(xin[(size_t)c * DIMO + l]);
        }
        acc += (v[0] + v[1]) + (v[2] + v[3]);
    }
    for (; e < cmain; e++) {
        int c = __shfl(cidx, e, 64);
        acc += __half2float(xin[(size_t)c * DIMO + l]);
    }
    for (int e2 = 64; e2 < cnt; e2++)
        acc += __half2float(xin[(size_t)col[rs + e2] * DIMO + l]);
    float di = dinv[node];
    if (lane < DIMO) {
        if (finalHop) outF[(size_t)node * DIMO + lane] = di * acc + bc[lane];
        else          xpart[(size_t)node * DIMO + lane] = __float2half(di * di * acc);
    }
}

// ---------------- launch ----------------

extern "C" void kernel_launch(void* const* d_in, const int* in_sizes, int n_in,
                              void* d_out, int out_size, void* d_ws, size_t ws_size,
                              hipStream_t stream) {
    const float* x     = (const float*)d_in[0];
    const int*   ei    = (const int*)d_in[1];
    const float* Wsgc  = (const float*)d_in[2];
    const float* bsgc  = (const float*)d_in[3];
    const float* Whead = (const float*)d_in[4];
    const float* bhead = (const float*)d_in[5];
    float* out = (float*)d_out;

    const int N = in_sizes[0] / DIMI;
    const int E = in_sizes[1] / 2;
    const int* src = ei;
    const int* dst = ei + E;
    const int nbk = (N + NPBK - 1) >> NBK_SHIFT;
    const int nHalf = N / 2;

    char* w = (char*)d_ws;
    auto carve = [&](size_t bytes) {
        char* p = w;
        w += (bytes + 255) & ~(size_t)255;
        return p;
    };
    int*   counts  = (int*)  carve((size_t)N * 4);      // fallback only
    int*   cursor  = (int*)  carve((size_t)N * 4);      // fallback only
    int*   off     = (int*)  carve((size_t)(N + 1) * 4);
    int*   mid     = (int*)  carve((size_t)N * 4);
    float* dinv    = (float*)carve((size_t)N * 4);
    int*   partial = (int*)  carve(1024 * 4);
    int*   col     = (int*)  carve((size_t)E * 4);
    float* Wc      = (float*)carve(DIMI * DIMO * 4);
    float* bc      = (float*)carve(DIMO * 4);
    int*   bcnt    = (int*)  carve((size_t)nbk * 4);
    // union: ebP (CSR staging, dead before k_projU) aliases xA/xB
    size_t xbytes  = (size_t)N * DIMO * 2;              // 8MB each
    size_t ebytes  = (size_t)nbk * BCAP * 4;
    size_t ubytes  = ebytes > 2 * xbytes ? ebytes : 2 * xbytes;
    char*  uni     = carve(ubytes);
    int*    ebP = (int*)uni;
    __half* xA  = (__half*)uni;
    __half* xB  = (__half*)(uni + xbytes);
    size_t total_need = (size_t)(w - (char*)d_ws);
    const bool useBuckets = (ws_size >= total_need) && (nbk <= NBKMAX);

    const int B = 256;
    int nbN = (N + B - 1) / B;
    int nbE = (E + B - 1) / B;

    k_wc<<<1, 256, 0, stream>>>(Wsgc, bsgc, Whead, bhead, Wc, bc, bcnt, nbk);

    if (useBuckets) {
        int nbA = (E + CHUNK - 1) / CHUNK;
        k_binA<<<nbA, B, 0, stream>>>(src, dst, bcnt, ebP, E, nbk);
        k_binBC<<<nbk, B, 0, stream>>>(bcnt, ebP, off, mid, dinv, col, N, nbk, nHalf);
    } else {
        k_zero<<<nbN, B, 0, stream>>>(counts, N);
        k_zero<<<nbN, B, 0, stream>>>(cursor, N);
        k_hist<<<nbE, B, 0, stream>>>(dst, counts, E);
        k_block_sums<<<nbN, B, 0, stream>>>(counts, partial, N);
        k_scan_partials<<<1, 1024, 0, stream>>>(partial, nbN);
        k_scan_final<<<nbN, B, 0, stream>>>(counts, partial, off, mid, dinv, N);
        k_scatter<<<nbE, B, 0, stream>>>(src, dst, off, cursor, col, E);
    }

    k_projU<<<nbN, B, 0, stream>>>(x, Wc, dinv, xA, N);

    // 3 hops, each split into src-half passes: xA -> xB -> xA -> out
    int hopBlocks = (N * 64 + B - 1) / B;
    k_hopA<<<hopBlocks, B, 0, stream>>>(xA, xB, off, mid, col, N);
    k_hopB<<<hopBlocks, B, 0, stream>>>(xA, xB, out, off, mid, col, dinv, bc, 0, N);
    k_hopA<<<hopBlocks, B, 0, stream>>>(xB, xA, off, mid, col, N);
    k_hopB<<<hopBlocks, B, 0, stream>>>(xB, xA, out, off, mid, col, dinv, bc, 0, N);
    k_hopA<<<hopBlocks, B, 0, stream>>>(xA, xB, off, mid, col, N);
    k_hopB<<<hopBlocks, B, 0, stream>>>(xA, xB, out, off, mid, col, dinv, bc, 1, N);
}

// Round 12
// 236.224 us; speedup vs baseline: 1.1735x; 1.1735x over previous
//
#include <hip/hip_runtime.h>
#include <hip/hip_bf16.h>
#include <hip/hip_fp16.h>

#define DIMI 64
#define DIMO 40

#define NBK_SHIFT 9
#define NPBK 512
#define NBKMAX 256
#define BCAP 9216
#define CHUNK 4096

// ---------------- CSR build: LDS-sorted counting-sort path ----------------

__global__ void k_zero(int* __restrict__ p, int n) {
    int i = blockIdx.x * blockDim.x + threadIdx.x;
    if (i < n) p[i] = 0;
}

// Phase A: bin CHUNK edges into 512-node buckets; LDS sort; coalesced writeout.
// Records packed: (src << 9) | (dst & 511)
__global__ void k_binA(const int* __restrict__ src, const int* __restrict__ dst,
                       int* __restrict__ bcnt, int* __restrict__ ebP,
                       int E, int nbk) {
    __shared__ int h[NBKMAX];
    __shared__ int lb[NBKMAX];
    __shared__ int lc[NBKMAX];
    __shared__ int gb[NBKMAX];
    __shared__ int eb[CHUNK];
    __shared__ unsigned char ebB[CHUNK];
    int t = threadIdx.x;
    int e0 = blockIdx.x * CHUNK;
    int e1 = min(e0 + CHUNK, E);
    int nE = e1 - e0;
    h[t] = 0;
    __syncthreads();
    int d[CHUNK / 256], s[CHUNK / 256];
    #pragma unroll
    for (int u = 0; u < CHUNK / 256; u++) {
        int idx = e0 + t + u * 256;
        if (idx < e1) {
            d[u] = dst[idx];
            s[u] = src[idx];
            atomicAdd(&h[d[u] >> NBK_SHIFT], 1);
        }
    }
    __syncthreads();
    int orig = h[t];
    for (int o = 1; o < 256; o <<= 1) {
        int v = (t >= o) ? h[t - o] : 0;
        __syncthreads();
        h[t] += v;
        __syncthreads();
    }
    lb[t] = h[t] - orig;
    lc[t] = 0;
    gb[t] = orig ? atomicAdd(&bcnt[t], orig) : 0;
    __syncthreads();
    #pragma unroll
    for (int u = 0; u < CHUNK / 256; u++) {
        int idx = e0 + t + u * 256;
        if (idx < e1) {
            int b = d[u] >> NBK_SHIFT;
            int r = atomicAdd(&lc[b], 1);
            int slot = lb[b] + r;
            eb[slot] = (s[u] << NBK_SHIFT) | (d[u] & (NPBK - 1));
            ebB[slot] = (unsigned char)b;
        }
    }
    __syncthreads();
    for (int i = t; i < nE; i += 256) {
        int b = ebB[i];
        int slot = gb[b] + (i - lb[b]);
        if (slot < BCAP) ebP[(size_t)b * BCAP + slot] = eb[i];
    }
}

// Fused phase B+C: computes own bucket prefix; per-bucket hist -> 512-wide
// scan -> off/dinv dense writes -> LDS place -> coalesced col writeout.
__global__ void k_binBC(const int* __restrict__ bcnt, const int* __restrict__ ebP,
                        int* __restrict__ off, float* __restrict__ dinv,
                        int* __restrict__ col, int N, int nbk) {
    __shared__ int sb[256];
    __shared__ int sh[NPBK];
    __shared__ int so[NPBK];
    __shared__ int slc[NPBK];
    __shared__ int scol[BCAP];
    int b = blockIdx.x, t = threadIdx.x;
    // bucket global prefix (inclusive scan of min(bcnt,BCAP))
    int bv = (t < nbk) ? min(bcnt[t], BCAP) : 0;
    sb[t] = bv;
    __syncthreads();
    for (int o = 1; o < 256; o <<= 1) {
        int u = (t >= o) ? sb[t - o] : 0;
        __syncthreads();
        sb[t] += u;
        __syncthreads();
    }
    int gbase = (b > 0) ? sb[b - 1] : 0;
    sh[t] = 0; sh[t + 256] = 0;
    __syncthreads();
    int n = min(bcnt[b], BCAP);
    size_t base = (size_t)b * BCAP;
    for (int i = t; i < n; i += 256)
        atomicAdd(&sh[ebP[base + i] & (NPBK - 1)], 1);
    __syncthreads();
    so[t] = sh[t]; so[t + 256] = sh[t + 256];
    __syncthreads();
    for (int o = 1; o < NPBK; o <<= 1) {
        int v0 = (t >= o) ? sh[t - o] : 0;
        int v1 = (t + 256 >= o) ? sh[t + 256 - o] : 0;
        __syncthreads();
        sh[t] += v0; sh[t + 256] += v1;
        __syncthreads();
    }
    int d0 = b << NBK_SHIFT;
    #pragma unroll
    for (int half = 0; half < 2; half++) {
        int j = t + half * 256;
        int orig = so[j];
        int excl = sh[j] - orig;
        int dd = d0 + j;
        if (dd < N) {
            off[dd] = gbase + excl;
            dinv[dd] = rsqrtf((float)(orig + 1));
        }
        so[j] = excl;
        slc[j] = 0;
    }
    if (t == 0 && b == nbk - 1) off[N] = gbase + n;  // sentinel
    __syncthreads();
    for (int i = t; i < n; i += 256) {
        int e = ebP[base + i];
        int local = e & (NPBK - 1);
        int r = atomicAdd(&slc[local], 1);
        scol[so[local] + r] = e >> NBK_SHIFT;   // src id
    }
    __syncthreads();
    for (int i = t; i < n; i += 256) col[gbase + i] = scol[i];
}

// ---------------- CSR build: fallback (random-write) path ----------------

__global__ void k_hist(const int* __restrict__ dst, int* __restrict__ counts, int E) {
    int i = blockIdx.x * blockDim.x + threadIdx.x;
    if (i < E) atomicAdd(&counts[dst[i]], 1);
}

__global__ void k_scatter(const int* __restrict__ src, const int* __restrict__ dst,
                          const int* __restrict__ off, int* __restrict__ cursor,
                          int* __restrict__ col, int E) {
    int i = blockIdx.x * blockDim.x + threadIdx.x;
    if (i < E) {
        int d = dst[i];
        int p = off[d] + atomicAdd(&cursor[d], 1);
        col[p] = src[i];
    }
}

__global__ void k_block_sums(const int* __restrict__ counts, int* __restrict__ partial, int n) {
    __shared__ int s[256];
    int i = blockIdx.x * 256 + threadIdx.x;
    s[threadIdx.x] = (i < n) ? counts[i] : 0;
    __syncthreads();
    for (int st = 128; st > 0; st >>= 1) {
        if (threadIdx.x < st) s[threadIdx.x] += s[threadIdx.x + st];
        __syncthreads();
    }
    if (threadIdx.x == 0) partial[blockIdx.x] = s[0];
}

__global__ void k_scan_partials(int* partial, int nb) {
    __shared__ int s[1024];
    int t = threadIdx.x;
    int orig = (t < nb) ? partial[t] : 0;
    s[t] = orig;
    __syncthreads();
    for (int o = 1; o < 1024; o <<= 1) {
        int v = (t >= o) ? s[t - o] : 0;
        __syncthreads();
        s[t] += v;
        __syncthreads();
    }
    if (t < nb) partial[t] = s[t] - orig;
}

__global__ void k_scan_final(const int* __restrict__ counts, const int* __restrict__ partial,
                             int* __restrict__ off, float* __restrict__ dinv, int n) {
    __shared__ int s[256];
    int t = threadIdx.x;
    int i = blockIdx.x * 256 + t;
    int orig = (i < n) ? counts[i] : 0;
    s[t] = orig;
    __syncthreads();
    for (int o = 1; o < 256; o <<= 1) {
        int v = (t >= o) ? s[t - o] : 0;
        __syncthreads();
        s[t] += v;
        __syncthreads();
    }
    if (i < n) {
        off[i] = s[t] - orig + partial[blockIdx.x];
        dinv[i] = rsqrtf((float)(orig + 1));
        if (i == n - 1) off[n] = s[t] + partial[blockIdx.x];
    }
}

// ---------------- dense math ----------------

// Wc = W_sgc @ W_head; bc = b_sgc @ W_head + b_head; also zeroes bcnt.
__global__ void k_wc(const float* __restrict__ Wsgc, const float* __restrict__ bsgc,
                     const float* __restrict__ Whead, const float* __restrict__ bhead,
                     float* __restrict__ Wc, float* __restrict__ bc,
                     int* __restrict__ bcnt, int nbk) {
    __shared__ float sA[DIMI * DIMI];
    __shared__ float sB[DIMI * DIMO];
    int t = threadIdx.x;
    for (int i = t; i < nbk; i += 256) bcnt[i] = 0;
    for (int i = t; i < DIMI * DIMI; i += 256) sA[i] = Wsgc[i];
    for (int i = t; i < DIMI * DIMO; i += 256) sB[i] = Whead[i];
    __syncthreads();
    for (int o = t; o < DIMI * DIMO; o += 256) {
        int k = o / DIMO, j = o % DIMO;
        float a = 0.f;
        #pragma unroll
        for (int m = 0; m < DIMI; m++) a += sA[k * DIMI + m] * sB[m * DIMO + j];
        Wc[o] = a;
    }
    if (t < DIMO) {
        float a = bhead[t];
        #pragma unroll
        for (int m = 0; m < DIMI; m++) a += bsgc[m] * sB[m * DIMO + t];
        bc[t] = a;
    }
}

// u0 = dinv * (x @ Wc) -> unified fp16 rows, stride 40 (80B)
__global__ void k_projU(const float* __restrict__ x, const float* __restrict__ Wc,
                        const float* __restrict__ dinv, __half* __restrict__ y, int N) {
    __shared__ float sW[DIMI * DIMO];
    int t = threadIdx.x;
    for (int i = t; i < DIMI * DIMO; i += 256) sW[i] = Wc[i];
    __syncthreads();
    int node = blockIdx.x * 256 + t;
    if (node >= N) return;
    float di = dinv[node];
    const float4* xr = (const float4*)(x + (size_t)node * DIMI);
    float acc[DIMO];
    #pragma unroll
    for (int j = 0; j < DIMO; j++) acc[j] = 0.f;
    for (int k4 = 0; k4 < DIMI / 4; k4++) {
        float4 xv = xr[k4];
        int k = k4 * 4;
        #pragma unroll
        for (int j = 0; j < DIMO; j++)
            acc[j] += xv.x * sW[k * DIMO + j] + xv.y * sW[(k + 1) * DIMO + j]
                    + xv.z * sW[(k + 2) * DIMO + j] + xv.w * sW[(k + 3) * DIMO + j];
    }
    __half2* y2 = (__half2*)(y + (size_t)node * DIMO);
    #pragma unroll
    for (int p = 0; p < DIMO / 2; p++)
        y2[p] = __floats2half2_rn(di * acc[2 * p], di * acc[2 * p + 1]);
}

// Unified hop (round-10 champion): one 64-lane wave per node; lane = feature.
// fp16 rows, stride 40 (80B). nt loads for the single-use col/off streams
// (protect L2 for the gather slice); plain gather loads and plain stores.
__global__ void k_hop(const __half* __restrict__ xin, __half* __restrict__ xout,
                      float* __restrict__ outF,
                      const int* __restrict__ off, const float* __restrict__ dinv,
                      const int* __restrict__ col, const float* __restrict__ bc,
                      int finalHop, int N) {
    int gtid = blockIdx.x * blockDim.x + threadIdx.x;
    int node = gtid >> 6;
    int lane = threadIdx.x & 63;
    if (node >= N) return;
    int l = lane < DIMO ? lane : DIMO - 1;
    int rs = __builtin_nontemporal_load(off + node);
    int cnt = __builtin_nontemporal_load(off + node + 1) - rs;
    int cidx = (lane < cnt) ? __builtin_nontemporal_load(col + rs + lane) : node;
    float acc = __half2float(xin[(size_t)node * DIMO + l]);  // self loop
    int cmain = cnt < 64 ? cnt : 64;
    int e = 0;
    for (; e + 16 <= cmain; e += 16) {
        float v[16];
        #pragma unroll
        for (int u = 0; u < 16; u++) {
            int c = __shfl(cidx, e + u, 64);
            v[u] = __half2float(xin[(size_t)c * DIMO + l]);
        }
        float s01 = (v[0] + v[1]) + (v[2] + v[3]);
        float s23 = (v[4] + v[5]) + (v[6] + v[7]);
        float s45 = (v[8] + v[9]) + (v[10] + v[11]);
        float s67 = (v[12] + v[13]) + (v[14] + v[15]);
        acc += (s01 + s23) + (s45 + s67);
    }
    for (; e + 4 <= cmain; e += 4) {
        float v[4];
        #pragma unroll
        for (int u = 0; u < 4; u++) {
            int c = __shfl(cidx, e + u, 64);
            v[u] = __half2float(xin[(size_t)c * DIMO + l]);
        }
        acc += (v[0] + v[1]) + (v[2] + v[3]);
    }
    for (; e < cmain; e++) {
        int c = __shfl(cidx, e, 64);
        acc += __half2float(xin[(size_t)c * DIMO + l]);
    }
    for (int e2 = 64; e2 < cnt; e2++)   // deg>64: vanishingly rare
        acc += __half2float(xin[(size_t)col[rs + e2] * DIMO + l]);
    float di = dinv[node];
    if (lane < DIMO) {
        if (finalHop) outF[(size_t)node * DIMO + lane] = di * acc + bc[lane];
        else          xout[(size_t)node * DIMO + lane] = __float2half(di * di * acc);
    }
}

// ---------------- launch ----------------

extern "C" void kernel_launch(void* const* d_in, const int* in_sizes, int n_in,
                              void* d_out, int out_size, void* d_ws, size_t ws_size,
                              hipStream_t stream) {
    const float* x     = (const float*)d_in[0];
    const int*   ei    = (const int*)d_in[1];
    const float* Wsgc  = (const float*)d_in[2];
    const float* bsgc  = (const float*)d_in[3];
    const float* Whead = (const float*)d_in[4];
    const float* bhead = (const float*)d_in[5];
    float* out = (float*)d_out;

    const int N = in_sizes[0] / DIMI;
    const int E = in_sizes[1] / 2;
    const int* src = ei;
    const int* dst = ei + E;
    const int nbk = (N + NPBK - 1) >> NBK_SHIFT;

    char* w = (char*)d_ws;
    auto carve = [&](size_t bytes) {
        char* p = w;
        w += (bytes + 255) & ~(size_t)255;
        return p;
    };
    int*   counts  = (int*)  carve((size_t)N * 4);      // fallback only
    int*   cursor  = (int*)  carve((size_t)N * 4);      // fallback only
    int*   off     = (int*)  carve((size_t)(N + 1) * 4);
    float* dinv    = (float*)carve((size_t)N * 4);
    int*   partial = (int*)  carve(1024 * 4);
    int*   col     = (int*)  carve((size_t)E * 4);
    float* Wc      = (float*)carve(DIMI * DIMO * 4);
    float* bc      = (float*)carve(DIMO * 4);
    int*   bcnt    = (int*)  carve((size_t)nbk * 4);
    // union: ebP (CSR staging, dead before k_projU) aliases xA/xB
    size_t xbytes  = (size_t)N * DIMO * 2;              // 8MB each
    size_t ebytes  = (size_t)nbk * BCAP * 4;            // 7.2MB
    size_t ubytes  = ebytes > 2 * xbytes ? ebytes : 2 * xbytes;
    char*  uni     = carve(ubytes);
    int*    ebP = (int*)uni;
    __half* xA  = (__half*)uni;
    __half* xB  = (__half*)(uni + xbytes);
    size_t total_need = (size_t)(w - (char*)d_ws);
    const bool useBuckets = (ws_size >= total_need) && (nbk <= NBKMAX);

    const int B = 256;
    int nbN = (N + B - 1) / B;
    int nbE = (E + B - 1) / B;

    k_wc<<<1, 256, 0, stream>>>(Wsgc, bsgc, Whead, bhead, Wc, bc, bcnt, nbk);

    if (useBuckets) {
        int nbA = (E + CHUNK - 1) / CHUNK;
        k_binA<<<nbA, B, 0, stream>>>(src, dst, bcnt, ebP, E, nbk);
        k_binBC<<<nbk, B, 0, stream>>>(bcnt, ebP, off, dinv, col, N, nbk);
    } else {
        k_zero<<<nbN, B, 0, stream>>>(counts, N);
        k_zero<<<nbN, B, 0, stream>>>(cursor, N);
        k_hist<<<nbE, B, 0, stream>>>(dst, counts, E);
        k_block_sums<<<nbN, B, 0, stream>>>(counts, partial, N);
        k_scan_partials<<<1, 1024, 0, stream>>>(partial, nbN);
        k_scan_final<<<nbN, B, 0, stream>>>(counts, partial, off, dinv, N);
        k_scatter<<<nbE, B, 0, stream>>>(src, dst, off, cursor, col, E);
    }

    k_projU<<<nbN, B, 0, stream>>>(x, Wc, dinv, xA, N);

    // 3 hops: xA -> xB -> xA -> out(final: dinv scale + bias)
    int hopBlocks = (N * 64 + B - 1) / B;
    k_hop<<<hopBlocks, B, 0, stream>>>(xA, xB, out, off, dinv, col, bc, 0, N);
    k_hop<<<hopBlocks, B, 0, stream>>>(xB, xA, out, off, dinv, col, bc, 0, N);
    k_hop<<<hopBlocks, B, 0, stream>>>(xA, xB, out, off, dinv, col, bc, 1, N);
}

// Round 13
// 212.924 us; speedup vs baseline: 1.3019x; 1.1094x over previous
//
#include <hip/hip_runtime.h>
#include <hip/hip_bf16.h>
#include <hip/hip_fp16.h>

#define DIMI 64
#define DIMO 40

#define NBK_SHIFT 9
#define NPBK 512
#define NBKMAX 256
#define BCAP 9216
#define CHUNK 4096

// ---------------- CSR build: LDS-sorted counting-sort path ----------------

__global__ void k_zero(int* __restrict__ p, int n) {
    int i = blockIdx.x * blockDim.x + threadIdx.x;
    if (i < n) p[i] = 0;
}

// Phase A: bin CHUNK edges into 512-node buckets; LDS sort; coalesced writeout.
// Records packed: (src << 9) | (dst & 511)
__global__ void k_binA(const int* __restrict__ src, const int* __restrict__ dst,
                       int* __restrict__ bcnt, int* __restrict__ ebP,
                       int E, int nbk) {
    __shared__ int h[NBKMAX];
    __shared__ int lb[NBKMAX];
    __shared__ int lc[NBKMAX];
    __shared__ int gb[NBKMAX];
    __shared__ int eb[CHUNK];
    __shared__ unsigned char ebB[CHUNK];
    int t = threadIdx.x;
    int e0 = blockIdx.x * CHUNK;
    int e1 = min(e0 + CHUNK, E);
    int nE = e1 - e0;
    h[t] = 0;
    __syncthreads();
    int d[CHUNK / 256], s[CHUNK / 256];
    #pragma unroll
    for (int u = 0; u < CHUNK / 256; u++) {
        int idx = e0 + t + u * 256;
        if (idx < e1) {
            d[u] = dst[idx];
            s[u] = src[idx];
            atomicAdd(&h[d[u] >> NBK_SHIFT], 1);
        }
    }
    __syncthreads();
    int orig = h[t];
    for (int o = 1; o < 256; o <<= 1) {
        int v = (t >= o) ? h[t - o] : 0;
        __syncthreads();
        h[t] += v;
        __syncthreads();
    }
    lb[t] = h[t] - orig;
    lc[t] = 0;
    gb[t] = orig ? atomicAdd(&bcnt[t], orig) : 0;
    __syncthreads();
    #pragma unroll
    for (int u = 0; u < CHUNK / 256; u++) {
        int idx = e0 + t + u * 256;
        if (idx < e1) {
            int b = d[u] >> NBK_SHIFT;
            int r = atomicAdd(&lc[b], 1);
            int slot = lb[b] + r;
            eb[slot] = (s[u] << NBK_SHIFT) | (d[u] & (NPBK - 1));
            ebB[slot] = (unsigned char)b;
        }
    }
    __syncthreads();
    for (int i = t; i < nE; i += 256) {
        int b = ebB[i];
        int slot = gb[b] + (i - lb[b]);
        if (slot < BCAP) ebP[(size_t)b * BCAP + slot] = eb[i];
    }
}

// Fused phase B+C: computes own bucket prefix; per-bucket hist -> 512-wide
// scan -> off/dinv dense writes -> LDS place -> coalesced col writeout.
__global__ void k_binBC(const int* __restrict__ bcnt, const int* __restrict__ ebP,
                        int* __restrict__ off, float* __restrict__ dinv,
                        int* __restrict__ col, int N, int nbk) {
    __shared__ int sb[256];
    __shared__ int sh[NPBK];
    __shared__ int so[NPBK];
    __shared__ int slc[NPBK];
    __shared__ int scol[BCAP];
    int b = blockIdx.x, t = threadIdx.x;
    // bucket global prefix (inclusive scan of min(bcnt,BCAP))
    int bv = (t < nbk) ? min(bcnt[t], BCAP) : 0;
    sb[t] = bv;
    __syncthreads();
    for (int o = 1; o < 256; o <<= 1) {
        int u = (t >= o) ? sb[t - o] : 0;
        __syncthreads();
        sb[t] += u;
        __syncthreads();
    }
    int gbase = (b > 0) ? sb[b - 1] : 0;
    sh[t] = 0; sh[t + 256] = 0;
    __syncthreads();
    int n = min(bcnt[b], BCAP);
    size_t base = (size_t)b * BCAP;
    for (int i = t; i < n; i += 256)
        atomicAdd(&sh[ebP[base + i] & (NPBK - 1)], 1);
    __syncthreads();
    so[t] = sh[t]; so[t + 256] = sh[t + 256];
    __syncthreads();
    for (int o = 1; o < NPBK; o <<= 1) {
        int v0 = (t >= o) ? sh[t - o] : 0;
        int v1 = (t + 256 >= o) ? sh[t + 256 - o] : 0;
        __syncthreads();
        sh[t] += v0; sh[t + 256] += v1;
        __syncthreads();
    }
    int d0 = b << NBK_SHIFT;
    #pragma unroll
    for (int half = 0; half < 2; half++) {
        int j = t + half * 256;
        int orig = so[j];
        int excl = sh[j] - orig;
        int dd = d0 + j;
        if (dd < N) {
            off[dd] = gbase + excl;
            dinv[dd] = rsqrtf((float)(orig + 1));
        }
        so[j] = excl;
        slc[j] = 0;
    }
    if (t == 0 && b == nbk - 1) off[N] = gbase + n;  // sentinel
    __syncthreads();
    for (int i = t; i < n; i += 256) {
        int e = ebP[base + i];
        int local = e & (NPBK - 1);
        int r = atomicAdd(&slc[local], 1);
        scol[so[local] + r] = e >> NBK_SHIFT;   // src id
    }
    __syncthreads();
    for (int i = t; i < n; i += 256) col[gbase + i] = scol[i];
}

// ---------------- CSR build: fallback (random-write) path ----------------

__global__ void k_hist(const int* __restrict__ dst, int* __restrict__ counts, int E) {
    int i = blockIdx.x * blockDim.x + threadIdx.x;
    if (i < E) atomicAdd(&counts[dst[i]], 1);
}

__global__ void k_scatter(const int* __restrict__ src, const int* __restrict__ dst,
                          const int* __restrict__ off, int* __restrict__ cursor,
                          int* __restrict__ col, int E) {
    int i = blockIdx.x * blockDim.x + threadIdx.x;
    if (i < E) {
        int d = dst[i];
        int p = off[d] + atomicAdd(&cursor[d], 1);
        col[p] = src[i];
    }
}

__global__ void k_block_sums(const int* __restrict__ counts, int* __restrict__ partial, int n) {
    __shared__ int s[256];
    int i = blockIdx.x * 256 + threadIdx.x;
    s[threadIdx.x] = (i < n) ? counts[i] : 0;
    __syncthreads();
    for (int st = 128; st > 0; st >>= 1) {
        if (threadIdx.x < st) s[threadIdx.x] += s[threadIdx.x + st];
        __syncthreads();
    }
    if (threadIdx.x == 0) partial[blockIdx.x] = s[0];
}

__global__ void k_scan_partials(int* partial, int nb) {
    __shared__ int s[1024];
    int t = threadIdx.x;
    int orig = (t < nb) ? partial[t] : 0;
    s[t] = orig;
    __syncthreads();
    for (int o = 1; o < 1024; o <<= 1) {
        int v = (t >= o) ? s[t - o] : 0;
        __syncthreads();
        s[t] += v;
        __syncthreads();
    }
    if (t < nb) partial[t] = s[t] - orig;
}

__global__ void k_scan_final(const int* __restrict__ counts, const int* __restrict__ partial,
                             int* __restrict__ off, float* __restrict__ dinv, int n) {
    __shared__ int s[256];
    int t = threadIdx.x;
    int i = blockIdx.x * 256 + t;
    int orig = (i < n) ? counts[i] : 0;
    s[t] = orig;
    __syncthreads();
    for (int o = 1; o < 256; o <<= 1) {
        int v = (t >= o) ? s[t - o] : 0;
        __syncthreads();
        s[t] += v;
        __syncthreads();
    }
    if (i < n) {
        off[i] = s[t] - orig + partial[blockIdx.x];
        dinv[i] = rsqrtf((float)(orig + 1));
        if (i == n - 1) off[n] = s[t] + partial[blockIdx.x];
    }
}

// ---------------- dense math ----------------

// Wc = W_sgc @ W_head; bc = b_sgc @ W_head + b_head; also zeroes bcnt.
__global__ void k_wc(const float* __restrict__ Wsgc, const float* __restrict__ bsgc,
                     const float* __restrict__ Whead, const float* __restrict__ bhead,
                     float* __restrict__ Wc, float* __restrict__ bc,
                     int* __restrict__ bcnt, int nbk) {
    __shared__ float sA[DIMI * DIMI];
    __shared__ float sB[DIMI * DIMO];
    int t = threadIdx.x;
    for (int i = t; i < nbk; i += 256) bcnt[i] = 0;
    for (int i = t; i < DIMI * DIMI; i += 256) sA[i] = Wsgc[i];
    for (int i = t; i < DIMI * DIMO; i += 256) sB[i] = Whead[i];
    __syncthreads();
    for (int o = t; o < DIMI * DIMO; o += 256) {
        int k = o / DIMO, j = o % DIMO;
        float a = 0.f;
        #pragma unroll
        for (int m = 0; m < DIMI; m++) a += sA[k * DIMI + m] * sB[m * DIMO + j];
        Wc[o] = a;
    }
    if (t < DIMO) {
        float a = bhead[t];
        #pragma unroll
        for (int m = 0; m < DIMI; m++) a += bsgc[m] * sB[m * DIMO + t];
        bc[t] = a;
    }
}

// u0 = dinv * (x @ Wc) -> unified fp16 rows, stride 40 (80B)
__global__ void k_projU(const float* __restrict__ x, const float* __restrict__ Wc,
                        const float* __restrict__ dinv, __half* __restrict__ y, int N) {
    __shared__ float sW[DIMI * DIMO];
    int t = threadIdx.x;
    for (int i = t; i < DIMI * DIMO; i += 256) sW[i] = Wc[i];
    __syncthreads();
    int node = blockIdx.x * 256 + t;
    if (node >= N) return;
    float di = dinv[node];
    const float4* xr = (const float4*)(x + (size_t)node * DIMI);
    float acc[DIMO];
    #pragma unroll
    for (int j = 0; j < DIMO; j++) acc[j] = 0.f;
    for (int k4 = 0; k4 < DIMI / 4; k4++) {
        float4 xv = xr[k4];
        int k = k4 * 4;
        #pragma unroll
        for (int j = 0; j < DIMO; j++)
            acc[j] += xv.x * sW[k * DIMO + j] + xv.y * sW[(k + 1) * DIMO + j]
                    + xv.z * sW[(k + 2) * DIMO + j] + xv.w * sW[(k + 3) * DIMO + j];
    }
    __half2* y2 = (__half2*)(y + (size_t)node * DIMO);
    #pragma unroll
    for (int p = 0; p < DIMO / 2; p++)
        y2[p] = __floats2half2_rn(di * acc[2 * p], di * acc[2 * p + 1]);
}

// Unified hop (round-10 champion, plain loads): one 64-lane wave per node;
// lane = feature (40..63 dup lane 39). fp16 rows, stride 40 (80B).
__global__ void k_hop(const __half* __restrict__ xin, __half* __restrict__ xout,
                      float* __restrict__ outF,
                      const int* __restrict__ off, const float* __restrict__ dinv,
                      const int* __restrict__ col, const float* __restrict__ bc,
                      int finalHop, int N) {
    int gtid = blockIdx.x * blockDim.x + threadIdx.x;
    int node = gtid >> 6;
    int lane = threadIdx.x & 63;
    if (node >= N) return;
    int l = lane < DIMO ? lane : DIMO - 1;
    int rs = off[node];
    int cnt = off[node + 1] - rs;
    int cidx = (lane < cnt) ? col[rs + lane] : node;      // coalesced preload
    float acc = __half2float(xin[(size_t)node * DIMO + l]);  // self loop
    int cmain = cnt < 64 ? cnt : 64;
    int e = 0;
    for (; e + 16 <= cmain; e += 16) {
        float v[16];
        #pragma unroll
        for (int u = 0; u < 16; u++) {
            int c = __shfl(cidx, e + u, 64);
            v[u] = __half2float(xin[(size_t)c * DIMO + l]);
        }
        float s01 = (v[0] + v[1]) + (v[2] + v[3]);
        float s23 = (v[4] + v[5]) + (v[6] + v[7]);
        float s45 = (v[8] + v[9]) + (v[10] + v[11]);
        float s67 = (v[12] + v[13]) + (v[14] + v[15]);
        acc += (s01 + s23) + (s45 + s67);
    }
    for (; e + 4 <= cmain; e += 4) {
        float v[4];
        #pragma unroll
        for (int u = 0; u < 4; u++) {
            int c = __shfl(cidx, e + u, 64);
            v[u] = __half2float(xin[(size_t)c * DIMO + l]);
        }
        acc += (v[0] + v[1]) + (v[2] + v[3]);
    }
    for (; e < cmain; e++) {
        int c = __shfl(cidx, e, 64);
        acc += __half2float(xin[(size_t)c * DIMO + l]);
    }
    for (int e2 = 64; e2 < cnt; e2++)   // deg>64: vanishingly rare
        acc += __half2float(xin[(size_t)col[rs + e2] * DIMO + l]);
    float di = dinv[node];
    if (lane < DIMO) {
        if (finalHop) outF[(size_t)node * DIMO + lane] = di * acc + bc[lane];
        else          xout[(size_t)node * DIMO + lane] = __float2half(di * di * acc);
    }
}

// ---------------- launch ----------------

extern "C" void kernel_launch(void* const* d_in, const int* in_sizes, int n_in,
                              void* d_out, int out_size, void* d_ws, size_t ws_size,
                              hipStream_t stream) {
    const float* x     = (const float*)d_in[0];
    const int*   ei    = (const int*)d_in[1];
    const float* Wsgc  = (const float*)d_in[2];
    const float* bsgc  = (const float*)d_in[3];
    const float* Whead = (const float*)d_in[4];
    const float* bhead = (const float*)d_in[5];
    float* out = (float*)d_out;

    const int N = in_sizes[0] / DIMI;
    const int E = in_sizes[1] / 2;
    const int* src = ei;
    const int* dst = ei + E;
    const int nbk = (N + NPBK - 1) >> NBK_SHIFT;

    char* w = (char*)d_ws;
    auto carve = [&](size_t bytes) {
        char* p = w;
        w += (bytes + 255) & ~(size_t)255;
        return p;
    };
    int*   counts  = (int*)  carve((size_t)N * 4);      // fallback only
    int*   cursor  = (int*)  carve((size_t)N * 4);      // fallback only
    int*   off     = (int*)  carve((size_t)(N + 1) * 4);
    float* dinv    = (float*)carve((size_t)N * 4);
    int*   partial = (int*)  carve(1024 * 4);
    int*   col     = (int*)  carve((size_t)E * 4);
    float* Wc      = (float*)carve(DIMI * DIMO * 4);
    float* bc      = (float*)carve(DIMO * 4);
    int*   bcnt    = (int*)  carve((size_t)nbk * 4);
    // union: ebP (CSR staging, dead before k_projU) aliases xA/xB
    size_t xbytes  = (size_t)N * DIMO * 2;              // 8MB each
    size_t ebytes  = (size_t)nbk * BCAP * 4;            // 7.2MB
    size_t ubytes  = ebytes > 2 * xbytes ? ebytes : 2 * xbytes;
    char*  uni     = carve(ubytes);
    int*    ebP = (int*)uni;
    __half* xA  = (__half*)uni;
    __half* xB  = (__half*)(uni + xbytes);
    size_t total_need = (size_t)(w - (char*)d_ws);
    const bool useBuckets = (ws_size >= total_need) && (nbk <= NBKMAX);

    const int B = 256;
    int nbN = (N + B - 1) / B;
    int nbE = (E + B - 1) / B;

    k_wc<<<1, 256, 0, stream>>>(Wsgc, bsgc, Whead, bhead, Wc, bc, bcnt, nbk);

    if (useBuckets) {
        int nbA = (E + CHUNK - 1) / CHUNK;
        k_binA<<<nbA, B, 0, stream>>>(src, dst, bcnt, ebP, E, nbk);
        k_binBC<<<nbk, B, 0, stream>>>(bcnt, ebP, off, dinv, col, N, nbk);
    } else {
        k_zero<<<nbN, B, 0, stream>>>(counts, N);
        k_zero<<<nbN, B, 0, stream>>>(cursor, N);
        k_hist<<<nbE, B, 0, stream>>>(dst, counts, E);
        k_block_sums<<<nbN, B, 0, stream>>>(counts, partial, N);
        k_scan_partials<<<1, 1024, 0, stream>>>(partial, nbN);
        k_scan_final<<<nbN, B, 0, stream>>>(counts, partial, off, dinv, N);
        k_scatter<<<nbE, B, 0, stream>>>(src, dst, off, cursor, col, E);
    }

    k_projU<<<nbN, B, 0, stream>>>(x, Wc, dinv, xA, N);

    // 3 hops: xA -> xB -> xA -> out(final: dinv scale + bias)
    int hopBlocks = (N * 64 + B - 1) / B;
    k_hop<<<hopBlocks, B, 0, stream>>>(xA, xB, out, off, dinv, col, bc, 0, N);
    k_hop<<<hopBlocks, B, 0, stream>>>(xB, xA, out, off, dinv, col, bc, 0, N);
    k_hop<<<hopBlocks, B, 0, stream>>>(xA, xB, out, off, dinv, col, bc, 1, N);
}